// Round 6
// baseline (591.514 us; speedup 1.0000x reference)
//
#include <hip/hip_runtime.h>
#include <cstdint>
#include <cstddef>

// Problem shape (fixed by the reference): B=8, C=192, Tx=512, Ty=2048.
#define BB 8
#define CC 192
#define TXX 512
#define TYY 2048
#define NG_MAX (TYY / 8)   // 256 groups of 8 rows

#define NEG_INF (-1e9f)
#define HALF_LOG_2PI 0.9189385332046727f  // 0.5*log(2*pi)

// ---- output layout (floats, concatenated in return order) ----
#define O1 8388608
#define O2 11534336
#define O3 14680064
#define O4 14680065

// ---- workspace layout (bytes) ----
#define WS_NEG   0           // neg_cent fp32 [B,Ty,Tx]           33,554,432 B
#define WS_S     33554432    // s_p_sq_r [B,C,Tx]                  3,145,728 B
#define WS_MSR   36700160    // m_p * s  [B,C,Tx]                  3,145,728 B
#define WS_BIAS  39845888    // nc1+nc4  [B,Tx]                       16,384 B
#define WS_DIRS  39862272    // dir bits [B,Ty/4,64] dwords        1,048,576 B
#define WS_IDX   40910848    // idx_map  [B,Ty] int                   65,536 B
#define WS_LENS  40976384    // int text_len[8], spec_len[8]             64 B
#define WS_PART  40976448    // kl partials [3072] float              12,288 B

typedef float f32x4 __attribute__((ext_vector_type(4)));

// ---------------------------------------------------------------------------
__global__ void k_zero(float* __restrict__ out) {
    int64_t i = (int64_t)blockIdx.x * blockDim.x + threadIdx.x;
    const int64_t n4 = (int64_t)BB * TYY * TXX / 4;
    float4 z4 = make_float4(0.f, 0.f, 0.f, 0.f);
    float4* p4 = (float4*)out;
    for (int64_t k = i; k < n4; k += (int64_t)gridDim.x * blockDim.x) p4[k] = z4;
    if (i < BB * TXX) out[O4 + i] = 0.0f;
}

__global__ void k_prep(const float* __restrict__ logs_p, const float* __restrict__ m_p,
                       float* __restrict__ s, float* __restrict__ msr) {
    int i = blockIdx.x * blockDim.x + threadIdx.x;
    float lp = logs_p[i], m = m_p[i];
    float sv = expf(-2.0f * lp);
    s[i] = sv;
    msr[i] = m * sv;
}

// R20: 64 blocks x 64 threads (was 16x256) -> 64 CUs active instead of 16.
__global__ void k_bias(const float* __restrict__ logs_p, const float* __restrict__ m_p,
                       const float* __restrict__ msr, float* __restrict__ bias) {
    int i = blockIdx.x * blockDim.x + threadIdx.x;  // B*Tx = 4096 threads
    int b = i >> 9, x = i & (TXX - 1);
    size_t base = (size_t)b * CC * TXX + x;
    const float* lpb = logs_p + base;
    const float* mb  = m_p + base;
    const float* msb = msr + base;
    float acc = 0.f;
#pragma unroll 8
    for (int c = 0; c < CC; ++c)
        acc += -HALF_LOG_2PI - lpb[(size_t)c * TXX] - 0.5f * mb[(size_t)c * TXX] * msb[(size_t)c * TXX];
    bias[i] = acc;
}

__global__ void k_len(const float* __restrict__ tmask, const float* __restrict__ smask,
                      int* __restrict__ lens) {
    __shared__ float red[256];
    int b = blockIdx.x, tid = threadIdx.x;
    float ts = 0.f;
    for (int i = tid; i < TXX; i += 256) ts += tmask[b * TXX + i];
    red[tid] = ts; __syncthreads();
    for (int s = 128; s > 0; s >>= 1) { if (tid < s) red[tid] += red[tid + s]; __syncthreads(); }
    if (tid == 0) lens[b] = (int)(red[0] + 0.5f);
    __syncthreads();
    float ss = 0.f;
    for (int i = tid; i < TYY; i += 256) ss += smask[b * TYY + i];
    red[tid] = ss; __syncthreads();
    for (int s = 128; s > 0; s >>= 1) { if (tid < s) red[tid] += red[tid + s]; __syncthreads(); }
    if (tid == 0) lens[8 + b] = (int)(red[0] + 0.5f);
}

// neg_cent GEMM (R11 v1 tile: 64x64, BK=16, 8 blocks/CU).
// Masked tiles exit early (block-uniform). Poison in masked region is
// harmless to the DP/backtrack (see R14 note).
__global__ __launch_bounds__(256) void k_gemm(const float* __restrict__ z,
                                              const float* __restrict__ msr,
                                              const float* __restrict__ sarr,
                                              const float* __restrict__ bias,
                                              const int* __restrict__ lens,
                                              float* __restrict__ neg) {
    int x0 = blockIdx.x * 64, t0 = blockIdx.y * 64, b = blockIdx.z;
    if (x0 >= lens[b] || t0 >= lens[8 + b]) return;   // masked tile

    __shared__ float Zs[16][68], Ms[16][68], Ss[16][68];  // +4 pad
    int tid = threadIdx.x;
    int tx = tid & 15, ty = tid >> 4;
    const float* zb = z    + (size_t)b * CC * TYY;
    const float* mb = msr  + (size_t)b * CC * TXX;
    const float* sb = sarr + (size_t)b * CC * TXX;
    int lr = tid >> 4, lc = (tid & 15) * 4;
    float acc[4][4] = {};
    for (int k0 = 0; k0 < CC; k0 += 16) {
        float4 zv = *(const float4*)(zb + (size_t)(k0 + lr) * TYY + t0 + lc);
        float4 mv = *(const float4*)(mb + (size_t)(k0 + lr) * TXX + x0 + lc);
        float4 sv = *(const float4*)(sb + (size_t)(k0 + lr) * TXX + x0 + lc);
        __syncthreads();
        *(float4*)&Zs[lr][lc] = zv;
        *(float4*)&Ms[lr][lc] = mv;
        *(float4*)&Ss[lr][lc] = sv;
        __syncthreads();
#pragma unroll
        for (int k = 0; k < 16; ++k) {
            float4 a4  = *(const float4*)&Zs[k][ty * 4];
            float4 bm4 = *(const float4*)&Ms[k][tx * 4];
            float4 bs4 = *(const float4*)&Ss[k][tx * 4];
            float av[4]  = {a4.x, a4.y, a4.z, a4.w};
            float bmv[4] = {bm4.x, bm4.y, bm4.z, bm4.w};
            float bsv[4] = {bs4.x, bs4.y, bs4.z, bs4.w};
#pragma unroll
            for (int i2 = 0; i2 < 4; ++i2) {
                float a2 = -0.5f * av[i2] * av[i2];
#pragma unroll
                for (int j = 0; j < 4; ++j)
                    acc[i2][j] += av[i2] * bmv[j] + a2 * bsv[j];
            }
        }
    }
    float4 b4 = *(const float4*)(bias + b * TXX + x0 + tx * 4);
    float bv[4] = {b4.x, b4.y, b4.z, b4.w};
#pragma unroll
    for (int i2 = 0; i2 < 4; ++i2) {
        int t = t0 + ty * 4 + i2;
        float4 o;
        o.x = acc[i2][0] + bv[0]; o.y = acc[i2][1] + bv[1];
        o.z = acc[i2][2] + bv[2]; o.w = acc[i2][3] + bv[3];
        *(float4*)(neg + ((size_t)b * TYY + t) * TXX + x0 + tx * 4) = o;
    }
}

// ---------------------------------------------------------------------------
// MAS forward v9 (R20): v8 LDS-ring staging + REGISTER DOUBLE-BUFFERED group
// tiles, reordered so every wait is provably cold; backtrack fused as tail.
//
// R19 post-mortem: per-SIMD-normalized VALUBusy (x128, 8 SIMDs of 1024) is
// ~54%, i.e. ~143cy/row VALU issue + ~120cy/row stall. The stall matches
// v8's serialization: LOADQ's ds_reads issued after the vm gate and consumed
// immediately (first-use lgkm ~120cy+/group), STAGE between wait and compute.
//
// v9 iteration on group g (cur regs hold g, loaded LAST iteration):
//   W_VM(N)      ensure L_{g+1} staged-complete (issued 3 iters ago: free)
//   lgkmcnt(0)   drains cur's ds_reads (issued 1 iter ago: free); makes
//                slot g&3 safe to overwrite
//   STAGE(g+4)   -> slot (g+4)&3 == g&3
//   LOADQ nxt    <- slot (g+1)&3 (consumed NEXT iter: latency hidden)
//   DPROWS(cur)  8 rows from resident registers, 2 dir stores
// vmcnt induction (per-iter VM issue: 16 loads then 2 stores):
//   steady (g>=3): after L_{g+1}: S(2)+L_{g+2}(16)+S(2)+L_{g+3}(16)+S(2)=38
//   g<3: W(32) (stricter, covers 32/34/36); tails: W(22), W(6).
// DPP boundary: old = NEG_INF + bound_ctrl=false -> lane0 takes old; the
// per-row lane0 cndmask is gone. x==y fold via per-group masks (v8-proven).
// Backtrack (k_bwd body) fused after WAIT_VM(0): dirs L2-hot, one launch
// saved. Dirs layout unchanged.
// ---------------------------------------------------------------------------
#define WAIT_VM(N) do {                                                   \
    asm volatile("s_waitcnt vmcnt(" #N ")" ::: "memory");                 \
    __builtin_amdgcn_sched_barrier(0);                                    \
} while (0)

#define LGKM0 do {                                                        \
    asm volatile("s_waitcnt lgkmcnt(0)" ::: "memory");                    \
    __builtin_amdgcn_sched_barrier(0);                                    \
} while (0)

#define GLDS(GP, LP)                                                      \
    __builtin_amdgcn_global_load_lds(                                     \
        (__attribute__((address_space(1))) void*)(GP),                    \
        (__attribute__((address_space(3))) void*)(LP), 16, 0, 0)

// Stage group G (8 rows x 512 f = 16KB) into ring slot G&3 (v8-proven).
#define STAGE(G) do {                                                     \
    const char* gb_ = gsrc + (size_t)(G) * 16384;                         \
    char* lb_ = ring + (((G) & 3) * 16384);                               \
    _Pragma("unroll")                                                     \
    for (int c_ = 0; c_ < 16; ++c_)                                       \
        GLDS(gb_ + c_ * 1024, lb_ + c_ * 1024);                           \
} while (0)

// Load all 8 rows (16 x f32x4) of slot SLP into register tile P (a or b).
#define LOADQ(P, SLP) do {                                                \
    const char* sp_ = (const char*)(SLP) + lbase;                         \
    P##0l = *(const f32x4*)(sp_ + sw0);                                   \
    P##0h = *(const f32x4*)(sp_ + sw1);                                   \
    P##1l = *(const f32x4*)(sp_ + 2048 + sw0);                            \
    P##1h = *(const f32x4*)(sp_ + 2048 + sw1);                            \
    P##2l = *(const f32x4*)(sp_ + 4096 + sw0);                            \
    P##2h = *(const f32x4*)(sp_ + 4096 + sw1);                            \
    P##3l = *(const f32x4*)(sp_ + 6144 + sw0);                            \
    P##3h = *(const f32x4*)(sp_ + 6144 + sw1);                            \
    P##4l = *(const f32x4*)(sp_ + 8192 + sw0);                            \
    P##4h = *(const f32x4*)(sp_ + 8192 + sw1);                            \
    P##5l = *(const f32x4*)(sp_ + 10240 + sw0);                           \
    P##5h = *(const f32x4*)(sp_ + 10240 + sw1);                           \
    P##6l = *(const f32x4*)(sp_ + 12288 + sw0);                           \
    P##6h = *(const f32x4*)(sp_ + 12288 + sw1);                           \
    P##7l = *(const f32x4*)(sp_ + 14336 + sw0);                           \
    P##7h = *(const f32x4*)(sp_ + 14336 + sw1);                           \
} while (0)

// One DP row from registers (y>0 semantics; lane0 boundary folded into DPP
// via old=NEG_INF + bound_ctrl=false).
#define DPROW(QL, QH, R) do {                                                 \
    float s0_ = QL[0], s1_ = QL[1], s2_ = QL[2], s3_ = QL[3];                 \
    float s4_ = QH[0], s5_ = QH[1], s6_ = QH[2], s7_ = QH[3];                 \
    unsigned d_ = 0;                                                          \
    float pl_ = __int_as_float(__builtin_amdgcn_update_dpp(                   \
        ninf_i, __float_as_int(v[7]), 0x138, 0xF, 0xF, false));               \
    float n0_ = s0_ + fmaxf(v[0], pl_);  if (pl_  > v[0]) d_ |= 1u;           \
    float n1_ = s1_ + fmaxf(v[1], v[0]); if (v[0] > v[1]) d_ |= 2u;           \
    float n2_ = s2_ + fmaxf(v[2], v[1]); if (v[1] > v[2]) d_ |= 4u;           \
    float n3_ = s3_ + fmaxf(v[3], v[2]); if (v[2] > v[3]) d_ |= 8u;           \
    float n4_ = s4_ + fmaxf(v[4], v[3]); if (v[3] > v[4]) d_ |= 16u;          \
    float n5_ = s5_ + fmaxf(v[5], v[4]); if (v[4] > v[5]) d_ |= 32u;          \
    float n6_ = s6_ + fmaxf(v[6], v[5]); if (v[5] > v[6]) d_ |= 64u;          \
    float n7_ = s7_ + fmaxf(v[7], v[6]); if (v[6] > v[7]) d_ |= 128u;         \
    v[0] = n0_; v[1] = n1_; v[2] = n2_; v[3] = n3_;                           \
    v[4] = n4_; v[5] = n5_; v[6] = n6_; v[7] = n7_;                           \
    acc |= d_ << (((R) & 3) * 8);                                             \
} while (0)

#define DPROWS(P, G) do {                                                     \
    unsigned fm0_ = (lane == (G)) ? 0x08040201u : 0u;                         \
    unsigned fm1_ = (lane == (G)) ? 0x80402010u : 0u;                         \
    uint32_t* dp_ = db32 + ((unsigned)(G) << 7) + lane;                       \
    DPROW(P##0l, P##0h, 0); DPROW(P##1l, P##1h, 1);                           \
    DPROW(P##2l, P##2h, 2); DPROW(P##3l, P##3h, 3);                           \
    dp_[0] = acc | fm0_; acc = 0;                                             \
    DPROW(P##4l, P##4h, 4); DPROW(P##5l, P##5h, 5);                           \
    DPROW(P##6l, P##6h, 6); DPROW(P##7l, P##7h, 7);                           \
    dp_[64] = acc | fm1_; acc = 0;                                            \
} while (0)

// One pipelined iteration: consume CURP (group g), prefetch NXTP (group g+1).
#define PHASE(CURP, NXTP) do {                                                \
    if (g == ng - 1) { DPROWS(CURP, g); goto fwd_done; }                      \
    if (g + 3 < ng) { if (g >= 3) { WAIT_VM(38); } else { WAIT_VM(32); } }    \
    else if (g + 2 < ng) { WAIT_VM(22); }                                     \
    else { WAIT_VM(6); }                                                      \
    LGKM0;                                                                    \
    if (g + 4 < ng) STAGE(g + 4);                                             \
    LOADQ(NXTP, ring + (((g + 1) & 3) * 16384));                              \
    DPROWS(CURP, g);                                                          \
    ++g;                                                                      \
} while (0)

__global__ __launch_bounds__(64, 1) void k_fwd(const float* __restrict__ neg,
                                               const int* __restrict__ lens,
                                               uint32_t* __restrict__ dirs,
                                               int* __restrict__ idx_map) {
    __shared__ __align__(16) char ring[4 * 16384];   // 64 KiB ring
    int b = blockIdx.x, lane = threadIdx.x;
    // global source pre-swizzle: lane fetches granule lane ^ ((lane>>3)&1)
    unsigned gsw = ((unsigned)lane * 16u) ^ ((((unsigned)lane >> 3) & 1u) << 4);
    const char* gsrc = (const char*)(neg + (size_t)b * TYY * TXX) + gsw;
    unsigned lbase = (unsigned)lane * 32u;
    unsigned sw0 = (((unsigned)lane >> 2) & 1u) << 4;   // swizzled lo offset
    unsigned sw1 = sw0 ^ 16u;                           // swizzled hi offset
    uint32_t* db32 = dirs + (size_t)b * (TYY / 4) * 64;
    int slen = lens[8 + b];
    int ng = (slen + 7) >> 3;    // 192..256 (slen >= 1536)
    int ninf_i = __float_as_int(NEG_INF);

    float v[8];
#pragma unroll
    for (int j = 0; j < 8; ++j) v[j] = NEG_INF;
    unsigned acc = 0;

    f32x4 a0l, a0h, a1l, a1h, a2l, a2h, a3l, a3h;
    f32x4 a4l, a4h, a5l, a5h, a6l, a6h, a7l, a7h;
    f32x4 b0l, b0h, b1l, b1h, b2l, b2h, b3l, b3h;
    f32x4 b4l, b4h, b5l, b5h, b6l, b6h, b7l, b7h;

    STAGE(0); STAGE(1); STAGE(2); STAGE(3);   // 4-group lead
    WAIT_VM(48);                              // L_0 complete
    LOADQ(a, ring);                           // tile A <- group 0

    // ---- iteration g=0 (row-0 special: only x==0 scored, no row-0 bits) ----
    WAIT_VM(32);                              // L_1 complete (<=32 after it)
    LGKM0;                                    // A's reads done (one-time stall)
    STAGE(4);                                 // -> slot 0 (safe now)
    LOADQ(b, ring + 16384);                   // tile B <- group 1
    {
        if (lane == 0) v[0] = a0l[0];
        unsigned fm0_ = (lane == 0) ? 0x08040201u : 0u;
        unsigned fm1_ = (lane == 0) ? 0x80402010u : 0u;
        uint32_t* dp_ = db32 + lane;
        DPROW(a1l, a1h, 1); DPROW(a2l, a2h, 2); DPROW(a3l, a3h, 3);
        dp_[0] = acc | fm0_; acc = 0;
        DPROW(a4l, a4h, 4); DPROW(a5l, a5h, 5);
        DPROW(a6l, a6h, 6); DPROW(a7l, a7h, 7);
        dp_[64] = acc | fm1_; acc = 0;
    }
    int g = 1;
    while (1) {
        PHASE(b, a);
        PHASE(a, b);
    }
fwd_done:
    // ---- fused backtrack (k_bwd body; dirs stores drained first) ----
    WAIT_VM(0);
    {
        int tlen = lens[b];
        int idx = tlen - 1;
        int y0 = slen - 1;
        while (y0 >= 0) {
            int nsteps = (y0 + 1 < 32) ? y0 + 1 : 32;
            int y = y0 - lane;
            int yy = (y < 0) ? 0 : y;
            int w0 = (idx >> 5) - 1;
            if (w0 < 0) w0 = 0;
            if (w0 > 14) w0 = 14;
            int qrow = (yy >> 2) * 64;
            int byteoff = (yy & 3) * 8;
            uint32_t lo = 0, hi = 0;
            if (lane < 32) {
#pragma unroll
                for (int k = 0; k < 4; ++k)
                    lo |= ((db32[qrow + 4 * w0 + k] >> byteoff) & 0xffu) << (8 * k);
#pragma unroll
                for (int k = 0; k < 4; ++k)
                    hi |= ((db32[qrow + 4 * w0 + 4 + k] >> byteoff) & 0xffu) << (8 * k);
            }
            int base = w0 << 5;
            int cap = 0;
#pragma unroll
            for (int j = 0; j < 32; ++j) {
                if (lane == j) cap = idx;
                uint32_t l = (uint32_t)__builtin_amdgcn_readlane((int)lo, j);
                uint32_t h = (uint32_t)__builtin_amdgcn_readlane((int)hi, j);
                int bp = idx - base;              // 0..63
                uint32_t word = (bp & 32) ? h : l;
                int bit = (int)((word >> (bp & 31)) & 1u);
                int move = (int)(idx != 0) & bit;
                idx -= move;
            }
            if (lane < nsteps) idx_map[b * TYY + (y0 - lane)] = cap;
            y0 -= 32;
        }
    }
}

// Scatter path one-hots + duration histogram from idx_map.
__global__ void k_scatter(const int* __restrict__ lens, const int* __restrict__ idx_map,
                          float* __restrict__ out) {
    int i = blockIdx.x * blockDim.x + threadIdx.x;  // B*Ty threads
    int b = i >> 11, y = i & (TYY - 1);
    if (y < lens[8 + b]) {
        int x = idx_map[i];
        out[(size_t)i * TXX + x] = 1.0f;
        atomicAdd(&out[O4 + b * TXX + x], 1.0f);
    }
}

// Gather m_p/logs_p onto spec frames via idx_map; fused KL partial sums.
__global__ __launch_bounds__(256) void k_gather(const float* __restrict__ z_p,
                                                const float* __restrict__ m_p,
                                                const float* __restrict__ logs_p,
                                                const float* __restrict__ logs_q,
                                                const int* __restrict__ lens,
                                                const int* __restrict__ idx_map,
                                                float* __restrict__ out,
                                                float* __restrict__ partials) {
    const int S = BB * CC * TYY / 4;
    int base = blockIdx.x * 256 + threadIdx.x;
    float klsum = 0.f;
#pragma unroll
    for (int r = 0; r < 4; ++r) {
        int i = base + r * S;
        int t = i & (TYY - 1);
        int bc = i >> 11;
        int b = bc / CC;
        float ma = 0.f, la = 0.f;
        if (t < lens[8 + b]) {
            int x = idx_map[b * TYY + t];
            size_t off = (size_t)bc * TXX + x;
            ma = m_p[off];
            la = logs_p[off];
            float zv = z_p[i], lq = logs_q[i];
            float dz = zv - ma;
            klsum += la - lq - 0.5f + 0.5f * dz * dz * expf(-2.0f * la);
        }
        out[O1 + i] = ma;
        out[O2 + i] = la;
    }
    for (int o = 32; o > 0; o >>= 1) klsum += __shfl_down(klsum, o);
    __shared__ float red[4];
    if ((threadIdx.x & 63) == 0) red[threadIdx.x >> 6] = klsum;
    __syncthreads();
    if (threadIdx.x == 0) partials[blockIdx.x] = red[0] + red[1] + red[2] + red[3];
}

__global__ void k_final(const float* __restrict__ partials, const int* __restrict__ lens,
                        float* __restrict__ out) {
    float s = 0.f;
    for (int i = threadIdx.x; i < 3072; i += 256) s += partials[i];
    for (int o = 32; o > 0; o >>= 1) s += __shfl_down(s, o);
    __shared__ float red[4];
    if ((threadIdx.x & 63) == 0) red[threadIdx.x >> 6] = s;
    __syncthreads();
    if (threadIdx.x == 0) {
        float tot = 0.f;
        for (int b = 0; b < 8; ++b) tot += (float)lens[8 + b];
        out[O3] = (red[0] + red[1] + red[2] + red[3]) / tot;
    }
}

extern "C" void kernel_launch(void* const* d_in, const int* in_sizes, int n_in,
                              void* d_out, int out_size, void* d_ws, size_t ws_size,
                              hipStream_t stream) {
    const float* z_p    = (const float*)d_in[0];
    const float* m_p    = (const float*)d_in[1];
    const float* logs_p = (const float*)d_in[2];
    const float* logs_q = (const float*)d_in[3];
    const float* tmask  = (const float*)d_in[4];
    const float* smask  = (const float*)d_in[5];
    float* out = (float*)d_out;
    char* ws = (char*)d_ws;

    float*    neg      = (float*)(ws + WS_NEG);
    float*    sarr     = (float*)(ws + WS_S);
    float*    msr      = (float*)(ws + WS_MSR);
    float*    bias     = (float*)(ws + WS_BIAS);
    uint32_t* dirs     = (uint32_t*)(ws + WS_DIRS);
    int*      idx_map  = (int*)(ws + WS_IDX);
    int*      lens     = (int*)(ws + WS_LENS);
    float*    partials = (float*)(ws + WS_PART);

    hipLaunchKernelGGL(k_zero,    dim3(2048),      dim3(256), 0, stream, out);
    hipLaunchKernelGGL(k_prep,    dim3(3072),      dim3(256), 0, stream, logs_p, m_p, sarr, msr);
    hipLaunchKernelGGL(k_bias,    dim3(64),        dim3(64),  0, stream, logs_p, m_p, msr, bias);
    hipLaunchKernelGGL(k_len,     dim3(8),         dim3(256), 0, stream, tmask, smask, lens);
    hipLaunchKernelGGL(k_gemm,    dim3(8, 32, 8),  dim3(256), 0, stream, z_p, msr, sarr, bias, lens, neg);
    hipLaunchKernelGGL(k_fwd,     dim3(8),         dim3(64),  0, stream, neg, lens, dirs, idx_map);
    hipLaunchKernelGGL(k_scatter, dim3(64),        dim3(256), 0, stream, lens, idx_map, out);
    hipLaunchKernelGGL(k_gather,  dim3(3072),      dim3(256), 0, stream, z_p, m_p, logs_p, logs_q,
                       lens, idx_map, out, partials);
    hipLaunchKernelGGL(k_final,   dim3(1),         dim3(256), 0, stream, partials, lens, out);
}